// Round 5
// baseline (344.971 us; speedup 1.0000x reference)
//
#include <hip/hip_runtime.h>
#include <hip/hip_bf16.h>
#include <math.h>

#define N_NODES 10000
#define N_EDGES 160000
#define D 512

typedef __attribute__((ext_vector_type(8))) short bf16x8;
typedef __attribute__((ext_vector_type(4))) float f32x4;

__device__ inline void gload_lds16(const void* g, void* l) {
    __builtin_amdgcn_global_load_lds(
        (const __attribute__((address_space(1))) void*)g,
        (__attribute__((address_space(3))) void*)l, 16, 0, 0);
}

__device__ inline float bf2f(short s) {
    return __uint_as_float(((unsigned int)(unsigned short)s) << 16);
}
__device__ inline short f2bf(float f) {
    __hip_bfloat16 h = __float2bfloat16(f);
    return *reinterpret_cast<short*>(&h);
}

// ---------------------------------------------------------------- prep

__global__ void zero2_kernel(int* __restrict__ c0, int* __restrict__ c1) {
    int i = blockIdx.x * blockDim.x + threadIdx.x;
    if (i < N_NODES) c0[i] = 0;
    else if (i < 2 * N_NODES) c1[i - N_NODES] = 0;
}

__global__ void deg2_kernel(const int* __restrict__ ein, const int* __restrict__ eout,
                            int* __restrict__ c0, int* __restrict__ c1) {
    int i = blockIdx.x * blockDim.x + threadIdx.x;
    if (i < N_EDGES) atomicAdd(&c0[ein[N_EDGES + i]], 1);
    else if (i < 2 * N_EDGES) atomicAdd(&c1[eout[N_EDGES + (i - N_EDGES)]], 1);
}

// blockIdx.x = branch. 10 elems/thread local scan + one block scan.
__global__ __launch_bounds__(1024) void scan2_kernel(
    const int* __restrict__ c0, const int* __restrict__ c1,
    int* __restrict__ r0, int* __restrict__ r1,
    float* __restrict__ dv0, float* __restrict__ dv1,
    int* __restrict__ f0, int* __restrict__ f1) {
    const int* cnt = blockIdx.x ? c1 : c0;
    int* rowp = blockIdx.x ? r1 : r0;
    float* dinv = blockIdx.x ? dv1 : dv0;
    int* fpos = blockIdx.x ? f1 : f0;
    __shared__ int sm[1024];
    const int t = threadIdx.x;
    const int base = t * 10;
    int local[10];
    int tsum = 0;
#pragma unroll
    for (int j = 0; j < 10; ++j) {
        int i = base + j;
        int v = (i < N_NODES) ? cnt[i] : 0;
        local[j] = tsum;
        tsum += v;
    }
    sm[t] = tsum;
    __syncthreads();
    for (int off = 1; off < 1024; off <<= 1) {
        int tv = (t >= off) ? sm[t - off] : 0;
        __syncthreads();
        sm[t] += tv;
        __syncthreads();
    }
    int carry = t ? sm[t - 1] : 0;
#pragma unroll
    for (int j = 0; j < 10; ++j) {
        int i = base + j;
        if (i < N_NODES) {
            int excl = carry + local[j];
            rowp[i] = excl;
            fpos[i] = excl;
            dinv[i] = rsqrtf((float)cnt[i] + 1.0f);
        }
    }
    if (t == 1023) rowp[N_NODES] = sm[1023];
}

__global__ void fill2_kernel(const int* __restrict__ ein, const int* __restrict__ eout,
                             const float* __restrict__ dv0, const float* __restrict__ dv1,
                             int* __restrict__ f0, int* __restrict__ f1,
                             int* __restrict__ es0, int* __restrict__ es1,
                             float* __restrict__ ec0, float* __restrict__ ec1) {
    int i = blockIdx.x * blockDim.x + threadIdx.x;
    if (i >= 2 * N_EDGES) return;
    int br = i >= N_EDGES;
    int e = i - br * N_EDGES;
    const int* ei = br ? eout : ein;
    const float* dinv = br ? dv1 : dv0;
    int* fpos = br ? f1 : f0;
    int* esrc = br ? es1 : es0;
    float* ecoef = br ? ec1 : ec0;
    int s = ei[e], d = ei[N_EDGES + e];
    int pos = atomicAdd(&fpos[d], 1);
    esrc[pos] = s;
    ecoef[pos] = dinv[s] * dinv[d];
}

// W[k][n] fp32 -> Bt[n][0..511]=hi, Bt[n][512..1023]=lo ; 4 matrices
__global__ void split_w4_kernel(const float* __restrict__ w0, const float* __restrict__ w1,
                                const float* __restrict__ w2, const float* __restrict__ w3,
                                __hip_bfloat16* __restrict__ t0, __hip_bfloat16* __restrict__ t1,
                                __hip_bfloat16* __restrict__ t2, __hip_bfloat16* __restrict__ t3) {
    int b = blockIdx.y;
    const float* W = (b == 0) ? w0 : (b == 1) ? w1 : (b == 2) ? w2 : w3;
    __hip_bfloat16* Bt = (b == 0) ? t0 : (b == 1) ? t1 : (b == 2) ? t2 : t3;
    int idx = blockIdx.x * blockDim.x + threadIdx.x;
    if (idx >= D * D) return;
    int k = idx >> 9, n = idx & 511;
    float v = W[k * D + n];
    __hip_bfloat16 h = __float2bfloat16(v);
    float lo = v - __bfloat162float(h);
    Bt[(size_t)n * 1024 + k] = h;
    Bt[(size_t)n * 1024 + 512 + k] = __float2bfloat16(lo);
}

// ------------------------------------------------------------ time encode

__global__ void te2_kernel(const float* __restrict__ x, const float* __restrict__ t,
                           const float* __restrict__ w0, const float* __restrict__ b0,
                           const float* __restrict__ w1, const float* __restrict__ b1,
                           __hip_bfloat16* __restrict__ o0, __hip_bfloat16* __restrict__ o1) {
    int idx = blockIdx.x * blockDim.x + threadIdx.x;
    if (idx >= 2 * N_NODES * 64) return;
    int br = idx >= N_NODES * 64;
    int r = idx - br * N_NODES * 64;
    const float* w = br ? w1 : w0;
    const float* b = br ? b1 : b0;
    short* out = (short*)(br ? o1 : o0);
    int i = r >> 6, j0 = (r & 63) * 8;
    float tv = t[i];
    float4 xa = *(const float4*)&x[(size_t)i * D + j0];
    float4 xb = *(const float4*)&x[(size_t)i * D + j0 + 4];
    float xv[8] = {xa.x, xa.y, xa.z, xa.w, xb.x, xb.y, xb.z, xb.w};
    bf16x8 o;
#pragma unroll
    for (int j = 0; j < 8; ++j)
        o[j] = f2bf(xv[j] + cosf(tv * w[j0 + j] + b[j0 + j]));
    *(bf16x8*)(out + (size_t)i * D + j0) = o;
}

// ---------------------------------------------------------------- MFMA GEMM
// C_bf16[M,512] = A_bf16[M,512] x Bt_split[512][1024]^T, 2-term (B hi+lo).
// 64x128 tile, BK=64, 16 K-steps. blockIdx.z = branch.

__global__ __launch_bounds__(256) void gemm_kernel(
    const __hip_bfloat16* __restrict__ A0, const __hip_bfloat16* __restrict__ A1,
    const __hip_bfloat16* __restrict__ B0, const __hip_bfloat16* __restrict__ B1,
    __hip_bfloat16* __restrict__ C0, __hip_bfloat16* __restrict__ C1, int M) {
    __shared__ __align__(16) char lds[2][24576];  // A 8KB | B 16KB
    const int tid = threadIdx.x, l = tid & 63, wid = tid >> 6;
    const int wm = wid >> 1, wn = wid & 1;
    const int bm = blockIdx.y * 64, bn = blockIdx.x * 128;
    const int bz = blockIdx.z;
    const int rl8 = l >> 3, sslot = (l & 7) ^ rl8;
    const short* Ap = (const short*)(bz ? A1 : A0);
    const short* Bp = (const short*)(bz ? B1 : B0);
    short* Cp = (short*)(bz ? C1 : C0);
    f32x4 acc[2][4] = {};

    auto stage = [&](int cur, int t) {
        int aoff = (t & 7) * 64;
        int boff = (t < 8) ? t * 64 : 512 + (t - 8) * 64;
        char* base = lds[cur];
#pragma unroll
        for (int j = 0; j < 2; ++j) {
            int rowl = wid * 16 + j * 8 + rl8;
            int grow = bm + rowl;
            if (grow > M - 1) grow = M - 1;
            gload_lds16(Ap + (size_t)grow * 512 + aoff + sslot * 8,
                        base + (wid * 16 + j * 8) * 128);
        }
#pragma unroll
        for (int j = 0; j < 4; ++j) {
            int rowl = wid * 32 + j * 8 + rl8;
            gload_lds16(Bp + (size_t)(bn + rowl) * 1024 + boff + sslot * 8,
                        base + 8192 + (wid * 32 + j * 8) * 128);
        }
    };

    auto compute = [&](int cur) {
        const char* baseA = lds[cur];
        const char* baseB = baseA + 8192;
        const int ra = wm * 32 + (l & 15);
        const int rb = wn * 64 + (l & 15);
#pragma unroll
        for (int kk = 0; kk < 2; ++kk) {
            int slot = kk * 4 + (l >> 4);
            bf16x8 af[2], bfr[4];
#pragma unroll
            for (int m = 0; m < 2; ++m) {
                int row = ra + m * 16;
                af[m] = *(const bf16x8*)(baseA + row * 128 + ((slot ^ (row & 7)) * 16));
            }
#pragma unroll
            for (int n = 0; n < 4; ++n) {
                int row = rb + n * 16;
                bfr[n] = *(const bf16x8*)(baseB + row * 128 + ((slot ^ (row & 7)) * 16));
            }
#pragma unroll
            for (int m = 0; m < 2; ++m)
#pragma unroll
                for (int n = 0; n < 4; ++n)
                    acc[m][n] = __builtin_amdgcn_mfma_f32_16x16x32_bf16(
                        af[m], bfr[n], acc[m][n], 0, 0, 0);
        }
    };

    stage(0, 0);
    __syncthreads();
    int cur = 0;
#pragma unroll 1
    for (int t = 0; t < 16; ++t) {
        if (t < 15) stage(cur ^ 1, t + 1);
        compute(cur);
        __syncthreads();
        cur ^= 1;
    }

    const int col0 = bn + wn * 64 + (l & 15);
    const int row0 = bm + wm * 32 + (l >> 4) * 4;
#pragma unroll
    for (int m = 0; m < 2; ++m)
#pragma unroll
        for (int n = 0; n < 4; ++n)
#pragma unroll
            for (int r = 0; r < 4; ++r) {
                int row = row0 + m * 16 + r;
                if (row < M) Cp[(size_t)row * D + col0 + n * 16] = f2bf(acc[m][n][r]);
            }
}

// ------------------------------------------------- feature-blocked aggregate
// 8 phases (branch x 4 fblocks of 128 feat), phase slowest -> per-XCD L2 holds
// the 2.5 MB slice. One wave per (node, phase); lane covers 2 features (4B).
// Edge (src,coef) shfl-broadcast from a 64-edge register batch.
// FINAL=0: out bf16 slice (+bias+self). FINAL=1: partial classifier dot.

template <int FINAL>
__global__ __launch_bounds__(256) void agg_fb_kernel(
    const __hip_bfloat16* __restrict__ h0, const __hip_bfloat16* __restrict__ h1,
    const int* __restrict__ rp0, const int* __restrict__ rp1,
    const int* __restrict__ es0, const int* __restrict__ es1,
    const float* __restrict__ ec0, const float* __restrict__ ec1,
    const float* __restrict__ dv0, const float* __restrict__ dv1,
    const float* __restrict__ bs0, const float* __restrict__ bs1,
    __hip_bfloat16* __restrict__ o0, __hip_bfloat16* __restrict__ o1,
    const float* __restrict__ fcw, float* __restrict__ zpart) {
    int sid = blockIdx.x * 4 + (threadIdx.x >> 6);   // 0..79999
    int lane = threadIdx.x & 63;
    int phase = sid / N_NODES;
    int node = sid - phase * N_NODES;
    int branch = phase >> 2, fb = phase & 3;
    int f0 = fb * 128 + lane * 2;

    const short* hp = (const short*)(branch ? h1 : h0);
    const int* rowp = branch ? rp1 : rp0;
    const int* esrc = branch ? es1 : es0;
    const float* ecoef = branch ? ec1 : ec0;
    const float* dinv = branch ? dv1 : dv0;
    const float* bias = branch ? bs1 : bs0;

    float a0 = 0.f, a1 = 0.f;
    int beg = rowp[node], end = rowp[node + 1];
    for (int base = beg; base < end; base += 64) {
        int e = base + lane;
        int s = 0;
        float c = 0.f;
        if (e < end) { s = esrc[e]; c = ecoef[e]; }
        int cnt = end - base;
        if (cnt > 64) cnt = 64;
        for (int j = 0; j < cnt; ++j) {
            int sj = __shfl(s, j);
            float cj = __shfl(c, j);
            unsigned int v = *(const unsigned int*)(hp + (size_t)sj * D + f0);
            a0 += cj * bf2f((short)(v & 0xffff));
            a1 += cj * bf2f((short)(v >> 16));
        }
    }
    float dvv = dinv[node];
    float selfc = dvv * dvv;
    {
        unsigned int v = *(const unsigned int*)(hp + (size_t)node * D + f0);
        a0 += selfc * bf2f((short)(v & 0xffff)) + bias[f0];
        a1 += selfc * bf2f((short)(v >> 16)) + bias[f0 + 1];
    }
    if (FINAL == 0) {
        short* op = (short*)(branch ? o1 : o0);
        unsigned int pk = ((unsigned int)(unsigned short)f2bf(a1) << 16) |
                          (unsigned short)f2bf(a0);
        *(unsigned int*)(op + (size_t)node * D + f0) = pk;
    } else {
        const float* fw = fcw + (size_t)(branch * D + f0) * 2;
        float z0 = a0 * fw[0] + a1 * fw[2];
        float z1 = a0 * fw[1] + a1 * fw[3];
#pragma unroll
        for (int off = 32; off; off >>= 1) {
            z0 += __shfl_down(z0, off);
            z1 += __shfl_down(z1, off);
        }
        if (lane == 0) {
            float2* zp = (float2*)zpart;
            zp[(size_t)phase * N_NODES + node] = make_float2(z0, z1);
        }
    }
}

// -------------------------------------------------- final log_softmax

__global__ void lsm_kernel(const float* __restrict__ zpart, const float* __restrict__ fcb,
                           float* __restrict__ out) {
    int node = blockIdx.x * blockDim.x + threadIdx.x;
    if (node >= N_NODES) return;
    const float2* zp = (const float2*)zpart;
    float z0 = fcb[0], z1 = fcb[1];
#pragma unroll
    for (int p = 0; p < 8; ++p) {
        float2 v = zp[(size_t)p * N_NODES + node];
        z0 += v.x;
        z1 += v.y;
    }
    float m = fmaxf(z0, z1);
    float l2 = m + logf(expf(z0 - m) + expf(z1 - m));
    out[node * 2 + 0] = z0 - l2;
    out[node * 2 + 1] = z1 - l2;
}

// ---------------------------------------------------------------- launch

extern "C" void kernel_launch(void* const* d_in, const int* in_sizes, int n_in,
                              void* d_out, int out_size, void* d_ws, size_t ws_size,
                              hipStream_t stream) {
    const float* x        = (const float*)d_in[0];
    const int*   ein      = (const int*)d_in[1];
    const int*   eout     = (const int*)d_in[2];
    const float* t        = (const float*)d_in[3];
    const float* te_w[2]  = {(const float*)d_in[4], (const float*)d_in[10]};
    const float* te_b[2]  = {(const float*)d_in[5], (const float*)d_in[11]};
    const float* W1[2]    = {(const float*)d_in[6], (const float*)d_in[12]};
    const float* b1[2]    = {(const float*)d_in[7], (const float*)d_in[13]};
    const float* W2[2]    = {(const float*)d_in[8], (const float*)d_in[14]};
    const float* b2[2]    = {(const float*)d_in[9], (const float*)d_in[15]};
    const float* fc_w     = (const float*)d_in[16];
    const float* fc_b     = (const float*)d_in[17];
    float* out = (float*)d_out;

    char* p = (char*)d_ws;
    auto carve = [&](size_t bytes) {
        void* r = (void*)p;
        p += ((bytes + 255) / 256) * 256;
        return r;
    };
    __hip_bfloat16* actA[2];  // te out / agg1 out
    __hip_bfloat16* actB[2];  // gemm out
    actA[0] = (__hip_bfloat16*)carve((size_t)N_NODES * D * 2);
    actA[1] = (__hip_bfloat16*)carve((size_t)N_NODES * D * 2);
    actB[0] = (__hip_bfloat16*)carve((size_t)N_NODES * D * 2);
    actB[1] = (__hip_bfloat16*)carve((size_t)N_NODES * D * 2);
    float* zpart = (float*)carve((size_t)8 * N_NODES * 2 * 4);
    __hip_bfloat16* W1t[2]; __hip_bfloat16* W2t[2];
    W1t[0] = (__hip_bfloat16*)carve((size_t)D * 1024 * 2);
    W1t[1] = (__hip_bfloat16*)carve((size_t)D * 1024 * 2);
    W2t[0] = (__hip_bfloat16*)carve((size_t)D * 1024 * 2);
    W2t[1] = (__hip_bfloat16*)carve((size_t)D * 1024 * 2);
    int*   cnt[2];   cnt[0]   = (int*)carve(N_NODES * 4);       cnt[1]   = (int*)carve(N_NODES * 4);
    float* dinv[2];  dinv[0]  = (float*)carve(N_NODES * 4);     dinv[1]  = (float*)carve(N_NODES * 4);
    int*   rowp[2];  rowp[0]  = (int*)carve((N_NODES + 1) * 4); rowp[1]  = (int*)carve((N_NODES + 1) * 4);
    int*   fpos[2];  fpos[0]  = (int*)carve(N_NODES * 4);       fpos[1]  = (int*)carve(N_NODES * 4);
    int*   esrc[2];  esrc[0]  = (int*)carve(N_EDGES * 4);       esrc[1]  = (int*)carve(N_EDGES * 4);
    float* ecoef[2]; ecoef[0] = (float*)carve(N_EDGES * 4);     ecoef[1] = (float*)carve(N_EDGES * 4);

    // ---- prep
    zero2_kernel<<<(2 * N_NODES + 255) / 256, 256, 0, stream>>>(cnt[0], cnt[1]);
    deg2_kernel<<<(2 * N_EDGES + 255) / 256, 256, 0, stream>>>(ein, eout, cnt[0], cnt[1]);
    scan2_kernel<<<2, 1024, 0, stream>>>(cnt[0], cnt[1], rowp[0], rowp[1],
                                         dinv[0], dinv[1], fpos[0], fpos[1]);
    fill2_kernel<<<(2 * N_EDGES + 255) / 256, 256, 0, stream>>>(
        ein, eout, dinv[0], dinv[1], fpos[0], fpos[1],
        esrc[0], esrc[1], ecoef[0], ecoef[1]);
    split_w4_kernel<<<dim3((D * D + 255) / 256, 4), 256, 0, stream>>>(
        W1[0], W2[0], W1[1], W2[1], W1t[0], W2t[0], W1t[1], W2t[1]);

    // ---- fused-branch pipeline
    dim3 gemm_grid(D / 128, (N_NODES + 63) / 64, 2);
    int agg_grid = 2 * N_NODES * 4 / 4;  // 80000 slices / 4 waves per block

    te2_kernel<<<(2 * N_NODES * 64 + 255) / 256, 256, 0, stream>>>(
        x, t, te_w[0], te_b[0], te_w[1], te_b[1], actA[0], actA[1]);
    gemm_kernel<<<gemm_grid, 256, 0, stream>>>(actA[0], actA[1], W1t[0], W1t[1],
                                               actB[0], actB[1], N_NODES);
    agg_fb_kernel<0><<<agg_grid, 256, 0, stream>>>(
        actB[0], actB[1], rowp[0], rowp[1], esrc[0], esrc[1], ecoef[0], ecoef[1],
        dinv[0], dinv[1], b1[0], b1[1], actA[0], actA[1], nullptr, nullptr);
    gemm_kernel<<<gemm_grid, 256, 0, stream>>>(actA[0], actA[1], W2t[0], W2t[1],
                                               actB[0], actB[1], N_NODES);
    agg_fb_kernel<1><<<agg_grid, 256, 0, stream>>>(
        actB[0], actB[1], rowp[0], rowp[1], esrc[0], esrc[1], ecoef[0], ecoef[1],
        dinv[0], dinv[1], b2[0], b2[1], nullptr, nullptr, fc_w, zpart);
    lsm_kernel<<<(N_NODES + 255) / 256, 256, 0, stream>>>(zpart, fc_b, out);
}

// Round 6
// 217.259 us; speedup vs baseline: 1.5878x; 1.5878x over previous
//
#include <hip/hip_runtime.h>
#include <hip/hip_bf16.h>
#include <math.h>

#define N_NODES 10000
#define N_EDGES 160000
#define D 512

typedef __attribute__((ext_vector_type(8))) short bf16x8;
typedef __attribute__((ext_vector_type(4))) float f32x4;

__device__ inline void gload_lds16(const void* g, void* l) {
    __builtin_amdgcn_global_load_lds(
        (const __attribute__((address_space(1))) void*)g,
        (__attribute__((address_space(3))) void*)l, 16, 0, 0);
}

__device__ inline float bf2f(short s) {
    return __uint_as_float(((unsigned int)(unsigned short)s) << 16);
}
__device__ inline short f2bf(float f) {
    __hip_bfloat16 h = __float2bfloat16(f);
    return *reinterpret_cast<short*>(&h);
}

// ---------------------------------------------------------------- prep

__global__ void zero2_kernel(int* __restrict__ c0, int* __restrict__ c1) {
    int i = blockIdx.x * blockDim.x + threadIdx.x;
    if (i < N_NODES) c0[i] = 0;
    else if (i < 2 * N_NODES) c1[i - N_NODES] = 0;
}

__global__ void deg2_kernel(const int* __restrict__ ein, const int* __restrict__ eout,
                            int* __restrict__ c0, int* __restrict__ c1) {
    int i = blockIdx.x * blockDim.x + threadIdx.x;
    if (i < N_EDGES) atomicAdd(&c0[ein[N_EDGES + i]], 1);
    else if (i < 2 * N_EDGES) atomicAdd(&c1[eout[N_EDGES + (i - N_EDGES)]], 1);
}

// blockIdx.x = branch. 10 elems/thread local scan + one block scan.
__global__ __launch_bounds__(1024) void scan2_kernel(
    const int* __restrict__ c0, const int* __restrict__ c1,
    int* __restrict__ r0, int* __restrict__ r1,
    float* __restrict__ dv0, float* __restrict__ dv1,
    int* __restrict__ f0, int* __restrict__ f1) {
    const int* cnt = blockIdx.x ? c1 : c0;
    int* rowp = blockIdx.x ? r1 : r0;
    float* dinv = blockIdx.x ? dv1 : dv0;
    int* fpos = blockIdx.x ? f1 : f0;
    __shared__ int sm[1024];
    const int t = threadIdx.x;
    const int base = t * 10;
    int local[10];
    int tsum = 0;
#pragma unroll
    for (int j = 0; j < 10; ++j) {
        int i = base + j;
        int v = (i < N_NODES) ? cnt[i] : 0;
        local[j] = tsum;
        tsum += v;
    }
    sm[t] = tsum;
    __syncthreads();
    for (int off = 1; off < 1024; off <<= 1) {
        int tv = (t >= off) ? sm[t - off] : 0;
        __syncthreads();
        sm[t] += tv;
        __syncthreads();
    }
    int carry = t ? sm[t - 1] : 0;
#pragma unroll
    for (int j = 0; j < 10; ++j) {
        int i = base + j;
        if (i < N_NODES) {
            int excl = carry + local[j];
            rowp[i] = excl;
            fpos[i] = excl;
            dinv[i] = rsqrtf((float)cnt[i] + 1.0f);
        }
    }
    if (t == 1023) rowp[N_NODES] = sm[1023];
}

__global__ void fill2_kernel(const int* __restrict__ ein, const int* __restrict__ eout,
                             const float* __restrict__ dv0, const float* __restrict__ dv1,
                             int* __restrict__ f0, int* __restrict__ f1,
                             int* __restrict__ es0, int* __restrict__ es1,
                             float* __restrict__ ec0, float* __restrict__ ec1) {
    int i = blockIdx.x * blockDim.x + threadIdx.x;
    if (i >= 2 * N_EDGES) return;
    int br = i >= N_EDGES;
    int e = i - br * N_EDGES;
    const int* ei = br ? eout : ein;
    const float* dinv = br ? dv1 : dv0;
    int* fpos = br ? f1 : f0;
    int* esrc = br ? es1 : es0;
    float* ecoef = br ? ec1 : ec0;
    int s = ei[e], d = ei[N_EDGES + e];
    int pos = atomicAdd(&fpos[d], 1);
    esrc[pos] = s;
    ecoef[pos] = dinv[s] * dinv[d];
}

// W[k][n] fp32 -> Bt[n][0..511]=hi, Bt[n][512..1023]=lo ; 2 matrices (W1 both branches)
__global__ void split_w2_kernel(const float* __restrict__ w0, const float* __restrict__ w1,
                                __hip_bfloat16* __restrict__ t0, __hip_bfloat16* __restrict__ t1) {
    int b = blockIdx.y;
    const float* W = b ? w1 : w0;
    __hip_bfloat16* Bt = b ? t1 : t0;
    int idx = blockIdx.x * blockDim.x + threadIdx.x;
    if (idx >= D * D) return;
    int k = idx >> 9, n = idx & 511;
    float v = W[k * D + n];
    __hip_bfloat16 h = __float2bfloat16(v);
    float lo = v - __bfloat162float(h);
    Bt[(size_t)n * 1024 + k] = h;
    Bt[(size_t)n * 1024 + 512 + k] = __float2bfloat16(lo);
}

// V[b][k] = sum_n W2_b[k][n] * fcw[(b*512+n)*2 + c]  (float2 over c)
// plus cvec = b2_in.F0 + b2_out.F1 + fcb (one wave)
__global__ __launch_bounds__(256) void vproj_kernel(
    const float* __restrict__ W2i, const float* __restrict__ W2o,
    const float* __restrict__ fcw, const float* __restrict__ fcb,
    const float* __restrict__ b2i, const float* __restrict__ b2o,
    float2* __restrict__ V, float2* __restrict__ cvec) {
    int tid = blockIdx.x * 256 + threadIdx.x;
    if (tid < 1024) {
        int b = tid >> 9, k = tid & 511;
        const float* W = b ? W2o : W2i;
        const float* F = fcw + b * 1024;
        float v0 = 0.f, v1 = 0.f;
        for (int n = 0; n < 512; ++n) {
            float w = W[k * 512 + n];
            v0 += w * F[2 * n];
            v1 += w * F[2 * n + 1];
        }
        V[tid] = make_float2(v0, v1);
    } else if (tid < 1088) {
        int lane = tid - 1024;
        float c0 = 0.f, c1 = 0.f;
        for (int n = lane; n < 512; n += 64) {
            c0 += b2i[n] * fcw[2 * n] + b2o[n] * fcw[2 * (512 + n)];
            c1 += b2i[n] * fcw[2 * n + 1] + b2o[n] * fcw[2 * (512 + n) + 1];
        }
#pragma unroll
        for (int off = 32; off; off >>= 1) {
            c0 += __shfl_down(c0, off);
            c1 += __shfl_down(c1, off);
        }
        if (lane == 0) *cvec = make_float2(c0 + fcb[0], c1 + fcb[1]);
    }
}

// ------------------------------------------------------------ time encode
// single pass over x: writes both branches' bf16 te outputs

__global__ void te2_kernel(const float* __restrict__ x, const float* __restrict__ t,
                           const float* __restrict__ w0, const float* __restrict__ b0,
                           const float* __restrict__ w1, const float* __restrict__ b1,
                           __hip_bfloat16* __restrict__ o0, __hip_bfloat16* __restrict__ o1) {
    int idx = blockIdx.x * blockDim.x + threadIdx.x;
    if (idx >= N_NODES * 64) return;
    int i = idx >> 6, j0 = (idx & 63) * 8;
    float tv = t[i];
    float4 xa = *(const float4*)&x[(size_t)i * D + j0];
    float4 xb = *(const float4*)&x[(size_t)i * D + j0 + 4];
    float xv[8] = {xa.x, xa.y, xa.z, xa.w, xb.x, xb.y, xb.z, xb.w};
    bf16x8 oa, ob;
#pragma unroll
    for (int j = 0; j < 8; ++j) {
        oa[j] = f2bf(xv[j] + cosf(tv * w0[j0 + j] + b0[j0 + j]));
        ob[j] = f2bf(xv[j] + cosf(tv * w1[j0 + j] + b1[j0 + j]));
    }
    *(bf16x8*)((short*)o0 + (size_t)i * D + j0) = oa;
    *(bf16x8*)((short*)o1 + (size_t)i * D + j0) = ob;
}

// ---------------------------------------------------------------- MFMA GEMM
// C_bf16[M,512] = A_bf16[M,512] x Bt_split[512][1024]^T, 2-term (B hi+lo).
// 64x128 tile, BK=64, 16 K-steps. blockIdx.z = branch.

__global__ __launch_bounds__(256) void gemm_kernel(
    const __hip_bfloat16* __restrict__ A0, const __hip_bfloat16* __restrict__ A1,
    const __hip_bfloat16* __restrict__ B0, const __hip_bfloat16* __restrict__ B1,
    __hip_bfloat16* __restrict__ C0, __hip_bfloat16* __restrict__ C1, int M) {
    __shared__ __align__(16) char lds[2][24576];  // A 8KB | B 16KB
    const int tid = threadIdx.x, l = tid & 63, wid = tid >> 6;
    const int wm = wid >> 1, wn = wid & 1;
    const int bm = blockIdx.y * 64, bn = blockIdx.x * 128;
    const int bz = blockIdx.z;
    const int rl8 = l >> 3, sslot = (l & 7) ^ rl8;
    const short* Ap = (const short*)(bz ? A1 : A0);
    const short* Bp = (const short*)(bz ? B1 : B0);
    short* Cp = (short*)(bz ? C1 : C0);
    f32x4 acc[2][4] = {};

    auto stage = [&](int cur, int t) {
        int aoff = (t & 7) * 64;
        int boff = (t < 8) ? t * 64 : 512 + (t - 8) * 64;
        char* base = lds[cur];
#pragma unroll
        for (int j = 0; j < 2; ++j) {
            int rowl = wid * 16 + j * 8 + rl8;
            int grow = bm + rowl;
            if (grow > M - 1) grow = M - 1;
            gload_lds16(Ap + (size_t)grow * 512 + aoff + sslot * 8,
                        base + (wid * 16 + j * 8) * 128);
        }
#pragma unroll
        for (int j = 0; j < 4; ++j) {
            int rowl = wid * 32 + j * 8 + rl8;
            gload_lds16(Bp + (size_t)(bn + rowl) * 1024 + boff + sslot * 8,
                        base + 8192 + (wid * 32 + j * 8) * 128);
        }
    };

    auto compute = [&](int cur) {
        const char* baseA = lds[cur];
        const char* baseB = baseA + 8192;
        const int ra = wm * 32 + (l & 15);
        const int rb = wn * 64 + (l & 15);
#pragma unroll
        for (int kk = 0; kk < 2; ++kk) {
            int slot = kk * 4 + (l >> 4);
            bf16x8 af[2], bfr[4];
#pragma unroll
            for (int m = 0; m < 2; ++m) {
                int row = ra + m * 16;
                af[m] = *(const bf16x8*)(baseA + row * 128 + ((slot ^ (row & 7)) * 16));
            }
#pragma unroll
            for (int n = 0; n < 4; ++n) {
                int row = rb + n * 16;
                bfr[n] = *(const bf16x8*)(baseB + row * 128 + ((slot ^ (row & 7)) * 16));
            }
#pragma unroll
            for (int m = 0; m < 2; ++m)
#pragma unroll
                for (int n = 0; n < 4; ++n)
                    acc[m][n] = __builtin_amdgcn_mfma_f32_16x16x32_bf16(
                        af[m], bfr[n], acc[m][n], 0, 0, 0);
        }
    };

    stage(0, 0);
    __syncthreads();
    int cur = 0;
#pragma unroll 1
    for (int t = 0; t < 16; ++t) {
        if (t < 15) stage(cur ^ 1, t + 1);
        compute(cur);
        __syncthreads();
        cur ^= 1;
    }

    const int col0 = bn + wn * 64 + (l & 15);
    const int row0 = bm + wm * 32 + (l >> 4) * 4;
#pragma unroll
    for (int m = 0; m < 2; ++m)
#pragma unroll
        for (int n = 0; n < 4; ++n)
#pragma unroll
            for (int r = 0; r < 4; ++r) {
                int row = row0 + m * 16 + r;
                if (row < M) Cp[(size_t)row * D + col0 + n * 16] = f2bf(acc[m][n][r]);
            }
}

// ------------------------------------------- aggregate + V-projection
// 1 wave per (node, branch); lane covers 8 features (16B row-slice loads).
// 4-deep pipelined edge loop (uniform esrc -> s_loads, 4 vmem in flight).
// Output: p[node] = (S . (g + b1 terms)) . V_b   -- 8 bytes per node.

__global__ __launch_bounds__(256) void agg_proj_kernel(
    const __hip_bfloat16* __restrict__ g0, const __hip_bfloat16* __restrict__ g1,
    const int* __restrict__ rp0, const int* __restrict__ rp1,
    const int* __restrict__ es0, const int* __restrict__ es1,
    const float* __restrict__ ec0, const float* __restrict__ ec1,
    const float* __restrict__ dv0, const float* __restrict__ dv1,
    const float* __restrict__ bs0, const float* __restrict__ bs1,
    const float2* __restrict__ V, float2* __restrict__ p0, float2* __restrict__ p1) {
    int sid = blockIdx.x * 4 + (threadIdx.x >> 6);
    if (sid >= 2 * N_NODES) return;
    int lane = threadIdx.x & 63;
    int branch = sid >= N_NODES;
    int node = sid - branch * N_NODES;
    const short* gp = (const short*)(branch ? g1 : g0);
    const int* rowp = branch ? rp1 : rp0;
    const int* esrc = branch ? es1 : es0;
    const float* ecoef = branch ? ec1 : ec0;
    const float* dinv = branch ? dv1 : dv0;
    const float* bias = branch ? bs1 : bs0;
    const int f0 = lane * 8;

    float acc[8] = {};
    int beg = rowp[node], end = rowp[node + 1];
    int e = beg;
#pragma unroll 1
    for (; e + 4 <= end; e += 4) {
        int s0 = esrc[e], s1 = esrc[e + 1], s2 = esrc[e + 2], s3 = esrc[e + 3];
        float c0 = ecoef[e], c1 = ecoef[e + 1], c2 = ecoef[e + 2], c3 = ecoef[e + 3];
        bf16x8 v0 = *(const bf16x8*)(gp + (size_t)s0 * D + f0);
        bf16x8 v1 = *(const bf16x8*)(gp + (size_t)s1 * D + f0);
        bf16x8 v2 = *(const bf16x8*)(gp + (size_t)s2 * D + f0);
        bf16x8 v3 = *(const bf16x8*)(gp + (size_t)s3 * D + f0);
#pragma unroll
        for (int j = 0; j < 8; ++j) {
            acc[j] += c0 * bf2f(v0[j]);
            acc[j] += c1 * bf2f(v1[j]);
            acc[j] += c2 * bf2f(v2[j]);
            acc[j] += c3 * bf2f(v3[j]);
        }
    }
#pragma unroll 1
    for (; e < end; ++e) {
        int s = esrc[e];
        float c = ecoef[e];
        bf16x8 v = *(const bf16x8*)(gp + (size_t)s * D + f0);
#pragma unroll
        for (int j = 0; j < 8; ++j) acc[j] += c * bf2f(v[j]);
    }
    float dvv = dinv[node];
    float selfc = dvv * dvv;
    {
        bf16x8 v = *(const bf16x8*)(gp + (size_t)node * D + f0);
#pragma unroll
        for (int j = 0; j < 8; ++j) acc[j] += selfc * bf2f(v[j]) + bias[f0 + j];
    }
    // project by V_b (512x2)
    const float2* Vb = V + branch * 512 + f0;
    float z0 = 0.f, z1 = 0.f;
#pragma unroll
    for (int j = 0; j < 8; ++j) {
        float2 w = Vb[j];
        z0 += acc[j] * w.x;
        z1 += acc[j] * w.y;
    }
#pragma unroll
    for (int off = 32; off; off >>= 1) {
        z0 += __shfl_down(z0, off);
        z1 += __shfl_down(z1, off);
    }
    if (lane == 0) {
        (branch ? p1 : p0)[node] = make_float2(z0, z1);
    }
}

// ------------------------------------- z = S_in.p_in + S_out.p_out + cvec ; lsm

__global__ __launch_bounds__(256) void zagg_lsm_kernel(
    const float2* __restrict__ p0, const float2* __restrict__ p1,
    const int* __restrict__ rp0, const int* __restrict__ rp1,
    const int* __restrict__ es0, const int* __restrict__ es1,
    const float* __restrict__ ec0, const float* __restrict__ ec1,
    const float* __restrict__ dv0, const float* __restrict__ dv1,
    const float2* __restrict__ cvec, float* __restrict__ out) {
    int node = blockIdx.x * 4 + (threadIdx.x >> 6);
    if (node >= N_NODES) return;
    int lane = threadIdx.x & 63;
    float z0 = 0.f, z1 = 0.f;
    {
        int beg = rp0[node], end = rp0[node + 1];
        for (int e = beg + lane; e < end; e += 64) {
            int s = es0[e];
            float c = ec0[e];
            float2 pv = p0[s];
            z0 += c * pv.x;
            z1 += c * pv.y;
        }
    }
    {
        int beg = rp1[node], end = rp1[node + 1];
        for (int e = beg + lane; e < end; e += 64) {
            int s = es1[e];
            float c = ec1[e];
            float2 pv = p1[s];
            z0 += c * pv.x;
            z1 += c * pv.y;
        }
    }
#pragma unroll
    for (int off = 32; off; off >>= 1) {
        z0 += __shfl_down(z0, off);
        z1 += __shfl_down(z1, off);
    }
    if (lane == 0) {
        float d0 = dv0[node], d1 = dv1[node];
        float2 a = p0[node], b = p1[node], cv = *cvec;
        z0 += d0 * d0 * a.x + d1 * d1 * b.x + cv.x;
        z1 += d0 * d0 * a.y + d1 * d1 * b.y + cv.y;
        float m = fmaxf(z0, z1);
        float l2 = m + logf(expf(z0 - m) + expf(z1 - m));
        out[node * 2 + 0] = z0 - l2;
        out[node * 2 + 1] = z1 - l2;
    }
}

// ---------------------------------------------------------------- launch

extern "C" void kernel_launch(void* const* d_in, const int* in_sizes, int n_in,
                              void* d_out, int out_size, void* d_ws, size_t ws_size,
                              hipStream_t stream) {
    const float* x        = (const float*)d_in[0];
    const int*   ein      = (const int*)d_in[1];
    const int*   eout     = (const int*)d_in[2];
    const float* t        = (const float*)d_in[3];
    const float* te_w[2]  = {(const float*)d_in[4], (const float*)d_in[10]};
    const float* te_b[2]  = {(const float*)d_in[5], (const float*)d_in[11]};
    const float* W1[2]    = {(const float*)d_in[6], (const float*)d_in[12]};
    const float* b1[2]    = {(const float*)d_in[7], (const float*)d_in[13]};
    const float* W2[2]    = {(const float*)d_in[8], (const float*)d_in[14]};
    const float* b2[2]    = {(const float*)d_in[9], (const float*)d_in[15]};
    const float* fc_w     = (const float*)d_in[16];
    const float* fc_b     = (const float*)d_in[17];
    float* out = (float*)d_out;

    char* p = (char*)d_ws;
    auto carve = [&](size_t bytes) {
        void* r = (void*)p;
        p += ((bytes + 255) / 256) * 256;
        return r;
    };
    __hip_bfloat16* actA[2];  // te out
    __hip_bfloat16* actB[2];  // gemm out (g tables)
    actA[0] = (__hip_bfloat16*)carve((size_t)N_NODES * D * 2);
    actA[1] = (__hip_bfloat16*)carve((size_t)N_NODES * D * 2);
    actB[0] = (__hip_bfloat16*)carve((size_t)N_NODES * D * 2);
    actB[1] = (__hip_bfloat16*)carve((size_t)N_NODES * D * 2);
    float2* pbuf[2];
    pbuf[0] = (float2*)carve((size_t)N_NODES * 8);
    pbuf[1] = (float2*)carve((size_t)N_NODES * 8);
    float2* V    = (float2*)carve((size_t)2 * 512 * 8);
    float2* cvec = (float2*)carve(256);
    __hip_bfloat16* W1t[2];
    W1t[0] = (__hip_bfloat16*)carve((size_t)D * 1024 * 2);
    W1t[1] = (__hip_bfloat16*)carve((size_t)D * 1024 * 2);
    int*   cnt[2];   cnt[0]   = (int*)carve(N_NODES * 4);       cnt[1]   = (int*)carve(N_NODES * 4);
    float* dinv[2];  dinv[0]  = (float*)carve(N_NODES * 4);     dinv[1]  = (float*)carve(N_NODES * 4);
    int*   rowp[2];  rowp[0]  = (int*)carve((N_NODES + 1) * 4); rowp[1]  = (int*)carve((N_NODES + 1) * 4);
    int*   fpos[2];  fpos[0]  = (int*)carve(N_NODES * 4);       fpos[1]  = (int*)carve(N_NODES * 4);
    int*   esrc[2];  esrc[0]  = (int*)carve(N_EDGES * 4);       esrc[1]  = (int*)carve(N_EDGES * 4);
    float* ecoef[2]; ecoef[0] = (float*)carve(N_EDGES * 4);     ecoef[1] = (float*)carve(N_EDGES * 4);

    // ---- prep
    zero2_kernel<<<(2 * N_NODES + 255) / 256, 256, 0, stream>>>(cnt[0], cnt[1]);
    deg2_kernel<<<(2 * N_EDGES + 255) / 256, 256, 0, stream>>>(ein, eout, cnt[0], cnt[1]);
    scan2_kernel<<<2, 1024, 0, stream>>>(cnt[0], cnt[1], rowp[0], rowp[1],
                                         dinv[0], dinv[1], fpos[0], fpos[1]);
    fill2_kernel<<<(2 * N_EDGES + 255) / 256, 256, 0, stream>>>(
        ein, eout, dinv[0], dinv[1], fpos[0], fpos[1],
        esrc[0], esrc[1], ecoef[0], ecoef[1]);
    split_w2_kernel<<<dim3((D * D + 255) / 256, 2), 256, 0, stream>>>(
        W1[0], W1[1], W1t[0], W1t[1]);
    vproj_kernel<<<5, 256, 0, stream>>>(W2[0], W2[1], fc_w, fc_b, b2[0], b2[1], V, cvec);

    // ---- pipeline
    dim3 gemm_grid(D / 128, (N_NODES + 63) / 64, 2);
    te2_kernel<<<(N_NODES * 64 + 255) / 256, 256, 0, stream>>>(
        x, t, te_w[0], te_b[0], te_w[1], te_b[1], actA[0], actA[1]);
    gemm_kernel<<<gemm_grid, 256, 0, stream>>>(actA[0], actA[1], W1t[0], W1t[1],
                                               actB[0], actB[1], N_NODES);
    agg_proj_kernel<<<(2 * N_NODES + 3) / 4, 256, 0, stream>>>(
        actB[0], actB[1], rowp[0], rowp[1], esrc[0], esrc[1], ecoef[0], ecoef[1],
        dinv[0], dinv[1], b1[0], b1[1], V, pbuf[0], pbuf[1]);
    zagg_lsm_kernel<<<(N_NODES + 3) / 4, 256, 0, stream>>>(
        pbuf[0], pbuf[1], rowp[0], rowp[1], esrc[0], esrc[1], ecoef[0], ecoef[1],
        dinv[0], dinv[1], cvec, out);
}

// Round 7
// 95.792 us; speedup vs baseline: 3.6013x; 2.2680x over previous
//
#include <hip/hip_runtime.h>
#include <hip/hip_bf16.h>
#include <math.h>

#define N_NODES 10000
#define N_EDGES 160000
#define D 512

// ---------------------------------------------------------------- prep

__global__ void zero2_kernel(int* __restrict__ c0, int* __restrict__ c1) {
    int i = blockIdx.x * blockDim.x + threadIdx.x;
    if (i < N_NODES) c0[i] = 0;
    else if (i < 2 * N_NODES) c1[i - N_NODES] = 0;
}

__global__ void deg2_kernel(const int* __restrict__ ein, const int* __restrict__ eout,
                            int* __restrict__ c0, int* __restrict__ c1) {
    int i = blockIdx.x * blockDim.x + threadIdx.x;
    if (i < N_EDGES) atomicAdd(&c0[ein[N_EDGES + i]], 1);
    else if (i < 2 * N_EDGES) atomicAdd(&c1[eout[N_EDGES + (i - N_EDGES)]], 1);
}

// blockIdx.x = branch. 10 elems/thread local scan + one block scan.
__global__ __launch_bounds__(1024) void scan2_kernel(
    const int* __restrict__ c0, const int* __restrict__ c1,
    int* __restrict__ r0, int* __restrict__ r1,
    float* __restrict__ dv0, float* __restrict__ dv1,
    int* __restrict__ f0, int* __restrict__ f1) {
    const int* cnt = blockIdx.x ? c1 : c0;
    int* rowp = blockIdx.x ? r1 : r0;
    float* dinv = blockIdx.x ? dv1 : dv0;
    int* fpos = blockIdx.x ? f1 : f0;
    __shared__ int sm[1024];
    const int t = threadIdx.x;
    const int base = t * 10;
    int local[10];
    int tsum = 0;
#pragma unroll
    for (int j = 0; j < 10; ++j) {
        int i = base + j;
        int v = (i < N_NODES) ? cnt[i] : 0;
        local[j] = tsum;
        tsum += v;
    }
    sm[t] = tsum;
    __syncthreads();
    for (int off = 1; off < 1024; off <<= 1) {
        int tv = (t >= off) ? sm[t - off] : 0;
        __syncthreads();
        sm[t] += tv;
        __syncthreads();
    }
    int carry = t ? sm[t - 1] : 0;
#pragma unroll
    for (int j = 0; j < 10; ++j) {
        int i = base + j;
        if (i < N_NODES) {
            int excl = carry + local[j];
            rowp[i] = excl;
            fpos[i] = excl;
            dinv[i] = rsqrtf((float)cnt[i] + 1.0f);
        }
    }
    if (t == 1023) rowp[N_NODES] = sm[1023];
}

__global__ void fill2_kernel(const int* __restrict__ ein, const int* __restrict__ eout,
                             const float* __restrict__ dv0, const float* __restrict__ dv1,
                             int* __restrict__ f0, int* __restrict__ f1,
                             int* __restrict__ es0, int* __restrict__ es1,
                             float* __restrict__ ec0, float* __restrict__ ec1) {
    int i = blockIdx.x * blockDim.x + threadIdx.x;
    if (i >= 2 * N_EDGES) return;
    int br = i >= N_EDGES;
    int e = i - br * N_EDGES;
    const int* ei = br ? eout : ein;
    const float* dinv = br ? dv1 : dv0;
    int* fpos = br ? f1 : f0;
    int* esrc = br ? es1 : es0;
    float* ecoef = br ? ec1 : ec0;
    int s = ei[e], d = ei[N_EDGES + e];
    int pos = atomicAdd(&fpos[d], 1);
    esrc[pos] = s;
    ecoef[pos] = dinv[s] * dinv[d];
}

// ------------------------------------------------ weight folding (rank-2)
// V_b[k,c] = sum_n W2_b[k][n] * F_b[n][c],  F_b[n][c] = fcw[(b*512+n)*2+c]
// wave per (b,k); lanes stride n (coalesced row read).

__global__ __launch_bounds__(256) void vproj_kernel(
    const float* __restrict__ W2i, const float* __restrict__ W2o,
    const float* __restrict__ fcw, float2* __restrict__ V) {
    int wv = blockIdx.x * 4 + (threadIdx.x >> 6);
    if (wv >= 1024) return;
    int lane = threadIdx.x & 63;
    int b = wv >> 9, k = wv & 511;
    const float* W = b ? W2o : W2i;
    const float* F = fcw + b * 1024;
    float v0 = 0.f, v1 = 0.f;
    for (int n = lane; n < 512; n += 64) {
        float w = W[k * 512 + n];
        v0 += w * F[2 * n];
        v1 += w * F[2 * n + 1];
    }
#pragma unroll
    for (int off = 32; off; off >>= 1) {
        v0 += __shfl_down(v0, off);
        v1 += __shfl_down(v1, off);
    }
    if (lane == 0) V[wv] = make_float2(v0, v1);
}

// U_b[j,c] = sum_k W1_b[j][k] * V_b[k,c]; tail wave: beta1_b = b1_b.V_b,
// cvec = fcb + b2_in.F0 + b2_out.F1

__global__ __launch_bounds__(256) void uproj_kernel(
    const float* __restrict__ W1i, const float* __restrict__ W1o,
    const float2* __restrict__ V,
    const float* __restrict__ b1i, const float* __restrict__ b1o,
    const float* __restrict__ b2i, const float* __restrict__ b2o,
    const float* __restrict__ fcw, const float* __restrict__ fcb,
    float2* __restrict__ U, float2* __restrict__ beta1, float2* __restrict__ cvec) {
    int wv = blockIdx.x * 4 + (threadIdx.x >> 6);
    int lane = threadIdx.x & 63;
    if (wv < 1024) {
        int b = wv >> 9, j = wv & 511;
        const float* W = b ? W1o : W1i;
        const float2* Vb = V + b * 512;
        float u0 = 0.f, u1 = 0.f;
        for (int k = lane; k < 512; k += 64) {
            float w = W[j * 512 + k];
            float2 v = Vb[k];
            u0 += w * v.x;
            u1 += w * v.y;
        }
#pragma unroll
        for (int off = 32; off; off >>= 1) {
            u0 += __shfl_down(u0, off);
            u1 += __shfl_down(u1, off);
        }
        if (lane == 0) U[wv] = make_float2(u0, u1);
    } else if (wv == 1024) {
        float a00 = 0.f, a01 = 0.f, a10 = 0.f, a11 = 0.f, c0 = 0.f, c1 = 0.f;
        for (int k = lane; k < 512; k += 64) {
            float2 v0 = V[k], v1 = V[512 + k];
            a00 += b1i[k] * v0.x;
            a01 += b1i[k] * v0.y;
            a10 += b1o[k] * v1.x;
            a11 += b1o[k] * v1.y;
            c0 += b2i[k] * fcw[2 * k] + b2o[k] * fcw[2 * (512 + k)];
            c1 += b2i[k] * fcw[2 * k + 1] + b2o[k] * fcw[2 * (512 + k) + 1];
        }
#pragma unroll
        for (int off = 32; off; off >>= 1) {
            a00 += __shfl_down(a00, off);
            a01 += __shfl_down(a01, off);
            a10 += __shfl_down(a10, off);
            a11 += __shfl_down(a11, off);
            c0 += __shfl_down(c0, off);
            c1 += __shfl_down(c1, off);
        }
        if (lane == 0) {
            beta1[0] = make_float2(a00, a01);
            beta1[1] = make_float2(a10, a11);
            *cvec = make_float2(c0 + fcb[0], c1 + fcb[1]);
        }
    }
}

// ------------------------------------------------ r_b[i] = TE_b[i,:] @ U_b
// wave per node; lane covers 8 features. 16 __cosf per lane.

__global__ __launch_bounds__(256) void r_kernel(
    const float* __restrict__ x, const float* __restrict__ t,
    const float* __restrict__ w0, const float* __restrict__ b0,
    const float* __restrict__ w1, const float* __restrict__ b1,
    const float2* __restrict__ U, float2* __restrict__ r0, float2* __restrict__ r1) {
    int node = blockIdx.x * 4 + (threadIdx.x >> 6);
    if (node >= N_NODES) return;
    int lane = threadIdx.x & 63;
    int j0 = lane * 8;
    float tv = t[node];
    float4 xa = *(const float4*)&x[(size_t)node * D + j0];
    float4 xb = *(const float4*)&x[(size_t)node * D + j0 + 4];
    float xv[8] = {xa.x, xa.y, xa.z, xa.w, xb.x, xb.y, xb.z, xb.w};
    float s00 = 0.f, s01 = 0.f, s10 = 0.f, s11 = 0.f;
#pragma unroll
    for (int j = 0; j < 8; ++j) {
        float xx = xv[j];
        float te0 = xx + __cosf(tv * w0[j0 + j] + b0[j0 + j]);
        float te1 = xx + __cosf(tv * w1[j0 + j] + b1[j0 + j]);
        float2 u0 = U[j0 + j];
        float2 u1 = U[512 + j0 + j];
        s00 += te0 * u0.x;
        s01 += te0 * u0.y;
        s10 += te1 * u1.x;
        s11 += te1 * u1.y;
    }
#pragma unroll
    for (int off = 32; off; off >>= 1) {
        s00 += __shfl_down(s00, off);
        s01 += __shfl_down(s01, off);
        s10 += __shfl_down(s10, off);
        s11 += __shfl_down(s11, off);
    }
    if (lane == 0) {
        r0[node] = make_float2(s00, s01);
        r1[node] = make_float2(s10, s11);
    }
}

// ------------------------------------------------ p_b = Shat_b . r_b + beta1_b
// wave per node; lanes 0..31 branch0, 32..63 branch1 (xor-butterfly stays in half)

__global__ __launch_bounds__(256) void pgather_kernel(
    const float2* __restrict__ r0, const float2* __restrict__ r1,
    const int* __restrict__ rp0, const int* __restrict__ rp1,
    const int* __restrict__ es0, const int* __restrict__ es1,
    const float* __restrict__ ec0, const float* __restrict__ ec1,
    const float* __restrict__ dv0, const float* __restrict__ dv1,
    const float2* __restrict__ beta1,
    float2* __restrict__ p0, float2* __restrict__ p1) {
    int node = blockIdx.x * 4 + (threadIdx.x >> 6);
    if (node >= N_NODES) return;
    int lane = threadIdx.x & 63;
    int half = lane >> 5, hl = lane & 31;
    const float2* rr = half ? r1 : r0;
    const int* rowp = half ? rp1 : rp0;
    const int* esrc = half ? es1 : es0;
    const float* ecoef = half ? ec1 : ec0;
    const float* dinv = half ? dv1 : dv0;
    float a0 = 0.f, a1 = 0.f;
    int beg = rowp[node], end = rowp[node + 1];
    for (int e = beg + hl; e < end; e += 32) {
        float c = ecoef[e];
        float2 v = rr[esrc[e]];
        a0 += c * v.x;
        a1 += c * v.y;
    }
#pragma unroll
    for (int m = 16; m; m >>= 1) {
        a0 += __shfl_xor(a0, m);
        a1 += __shfl_xor(a1, m);
    }
    if (hl == 0) {
        float dv = dinv[node];
        float sc = dv * dv;
        float2 rv = rr[node];
        float2 bb = beta1[half];
        (half ? p1 : p0)[node] = make_float2(a0 + sc * rv.x + bb.x,
                                             a1 + sc * rv.y + bb.y);
    }
}

// --------------------------------- z = sum_b Shat_b . p_b + cvec ; log_softmax

__global__ __launch_bounds__(256) void zlsm_kernel(
    const float2* __restrict__ p0, const float2* __restrict__ p1,
    const int* __restrict__ rp0, const int* __restrict__ rp1,
    const int* __restrict__ es0, const int* __restrict__ es1,
    const float* __restrict__ ec0, const float* __restrict__ ec1,
    const float* __restrict__ dv0, const float* __restrict__ dv1,
    const float2* __restrict__ cvec, float* __restrict__ out) {
    int node = blockIdx.x * 4 + (threadIdx.x >> 6);
    if (node >= N_NODES) return;
    int lane = threadIdx.x & 63;
    int half = lane >> 5, hl = lane & 31;
    const float2* pp = half ? p1 : p0;
    const int* rowp = half ? rp1 : rp0;
    const int* esrc = half ? es1 : es0;
    const float* ecoef = half ? ec1 : ec0;
    float a0 = 0.f, a1 = 0.f;
    int beg = rowp[node], end = rowp[node + 1];
    for (int e = beg + hl; e < end; e += 32) {
        float c = ecoef[e];
        float2 v = pp[esrc[e]];
        a0 += c * v.x;
        a1 += c * v.y;
    }
#pragma unroll
    for (int m = 16; m; m >>= 1) {
        a0 += __shfl_xor(a0, m);
        a1 += __shfl_xor(a1, m);
    }
    // combine halves
    a0 += __shfl_xor(a0, 32);
    a1 += __shfl_xor(a1, 32);
    if (lane == 0) {
        float d0 = dv0[node], d1 = dv1[node];
        float2 pa = p0[node], pb = p1[node], cv = *cvec;
        float z0 = a0 + d0 * d0 * pa.x + d1 * d1 * pb.x + cv.x;
        float z1 = a1 + d0 * d0 * pa.y + d1 * d1 * pb.y + cv.y;
        float m = fmaxf(z0, z1);
        float l2 = m + logf(expf(z0 - m) + expf(z1 - m));
        out[node * 2 + 0] = z0 - l2;
        out[node * 2 + 1] = z1 - l2;
    }
}

// ---------------------------------------------------------------- launch

extern "C" void kernel_launch(void* const* d_in, const int* in_sizes, int n_in,
                              void* d_out, int out_size, void* d_ws, size_t ws_size,
                              hipStream_t stream) {
    const float* x        = (const float*)d_in[0];
    const int*   ein      = (const int*)d_in[1];
    const int*   eout     = (const int*)d_in[2];
    const float* t        = (const float*)d_in[3];
    const float* te_w[2]  = {(const float*)d_in[4], (const float*)d_in[10]};
    const float* te_b[2]  = {(const float*)d_in[5], (const float*)d_in[11]};
    const float* W1[2]    = {(const float*)d_in[6], (const float*)d_in[12]};
    const float* b1[2]    = {(const float*)d_in[7], (const float*)d_in[13]};
    const float* W2[2]    = {(const float*)d_in[8], (const float*)d_in[14]};
    const float* b2[2]    = {(const float*)d_in[9], (const float*)d_in[15]};
    const float* fc_w     = (const float*)d_in[16];
    const float* fc_b     = (const float*)d_in[17];
    float* out = (float*)d_out;

    char* p = (char*)d_ws;
    auto carve = [&](size_t bytes) {
        void* r = (void*)p;
        p += ((bytes + 255) / 256) * 256;
        return r;
    };
    float2* V     = (float2*)carve((size_t)1024 * 8);
    float2* U     = (float2*)carve((size_t)1024 * 8);
    float2* beta1 = (float2*)carve(2 * 8);
    float2* cvec  = (float2*)carve(8);
    float2* rbuf[2];
    rbuf[0] = (float2*)carve((size_t)N_NODES * 8);
    rbuf[1] = (float2*)carve((size_t)N_NODES * 8);
    float2* pbuf[2];
    pbuf[0] = (float2*)carve((size_t)N_NODES * 8);
    pbuf[1] = (float2*)carve((size_t)N_NODES * 8);
    int*   cnt[2];   cnt[0]   = (int*)carve(N_NODES * 4);       cnt[1]   = (int*)carve(N_NODES * 4);
    float* dinv[2];  dinv[0]  = (float*)carve(N_NODES * 4);     dinv[1]  = (float*)carve(N_NODES * 4);
    int*   rowp[2];  rowp[0]  = (int*)carve((N_NODES + 1) * 4); rowp[1]  = (int*)carve((N_NODES + 1) * 4);
    int*   fpos[2];  fpos[0]  = (int*)carve(N_NODES * 4);       fpos[1]  = (int*)carve(N_NODES * 4);
    int*   esrc[2];  esrc[0]  = (int*)carve(N_EDGES * 4);       esrc[1]  = (int*)carve(N_EDGES * 4);
    float* ecoef[2]; ecoef[0] = (float*)carve(N_EDGES * 4);     ecoef[1] = (float*)carve(N_EDGES * 4);

    // ---- CSR prep
    zero2_kernel<<<(2 * N_NODES + 255) / 256, 256, 0, stream>>>(cnt[0], cnt[1]);
    deg2_kernel<<<(2 * N_EDGES + 255) / 256, 256, 0, stream>>>(ein, eout, cnt[0], cnt[1]);
    scan2_kernel<<<2, 1024, 0, stream>>>(cnt[0], cnt[1], rowp[0], rowp[1],
                                         dinv[0], dinv[1], fpos[0], fpos[1]);
    fill2_kernel<<<(2 * N_EDGES + 255) / 256, 256, 0, stream>>>(
        ein, eout, dinv[0], dinv[1], fpos[0], fpos[1],
        esrc[0], esrc[1], ecoef[0], ecoef[1]);

    // ---- rank-2 weight folding
    vproj_kernel<<<256, 256, 0, stream>>>(W2[0], W2[1], fc_w, V);
    uproj_kernel<<<257, 256, 0, stream>>>(W1[0], W1[1], V, b1[0], b1[1],
                                          b2[0], b2[1], fc_w, fc_b, U, beta1, cvec);

    // ---- collapsed pipeline
    r_kernel<<<(N_NODES + 3) / 4, 256, 0, stream>>>(
        x, t, te_w[0], te_b[0], te_w[1], te_b[1], U, rbuf[0], rbuf[1]);
    pgather_kernel<<<(N_NODES + 3) / 4, 256, 0, stream>>>(
        rbuf[0], rbuf[1], rowp[0], rowp[1], esrc[0], esrc[1], ecoef[0], ecoef[1],
        dinv[0], dinv[1], beta1, pbuf[0], pbuf[1]);
    zlsm_kernel<<<(N_NODES + 3) / 4, 256, 0, stream>>>(
        pbuf[0], pbuf[1], rowp[0], rowp[1], esrc[0], esrc[1], ecoef[0], ecoef[1],
        dinv[0], dinv[1], cvec, out);
}